// Round 6
// baseline (30.621 us; speedup 1.0000x reference)
//
#include <hip/hip_runtime.h>
#include <math.h>

#define N 512
#define C 256          // distinct label-diff classes per row (labels repeat)
#define D 128

// ---------------- K1: all-pairs logits via LDS-staged 32x32 tiles ----------------
__global__ __launch_bounds__(256) void k1_logits(const float* __restrict__ feat,
                                                 float* __restrict__ lg) {
    const int tid = threadIdx.x;
    const int row0 = (blockIdx.x >> 4) << 5;
    const int col0 = (blockIdx.x & 15) << 5;

    __shared__ float4 As[32][32];   // [row][swizzled q]
    __shared__ float4 Bs[32][32];

    const float4* f4 = (const float4*)feat;   // [512][32]
    {
        const int r = tid >> 5, c4 = tid & 31;
#pragma unroll
        for (int p = 0; p < 4; ++p) {
            const int rr = r + p * 8;
            const int sc = c4 ^ ((rr >> 1) & 7);
            As[rr][sc] = f4[(size_t)(row0 + rr) * 32 + c4];
            Bs[rr][sc] = f4[(size_t)(col0 + rr) * 32 + c4];
        }
    }
    __syncthreads();

    const int ty = tid >> 4, tx = tid & 15;
    const int r0 = 2 * ty, r1 = 2 * ty + 1;
    const int c0 = 2 * tx, c1 = 2 * tx + 1;
    const int sa = ty & 7, sb = tx & 7;

    float s00 = 0.f, s01 = 0.f, s10 = 0.f, s11 = 0.f;
#pragma unroll 8
    for (int q = 0; q < 32; ++q) {
        float4 a0 = As[r0][q ^ sa];
        float4 a1 = As[r1][q ^ sa];
        float4 b0 = Bs[c0][q ^ sb];
        float4 b1 = Bs[c1][q ^ sb];
        float t;
        t = a0.x - b0.x; s00 = fmaf(t, t, s00);
        t = a0.y - b0.y; s00 = fmaf(t, t, s00);
        t = a0.z - b0.z; s00 = fmaf(t, t, s00);
        t = a0.w - b0.w; s00 = fmaf(t, t, s00);
        t = a0.x - b1.x; s01 = fmaf(t, t, s01);
        t = a0.y - b1.y; s01 = fmaf(t, t, s01);
        t = a0.z - b1.z; s01 = fmaf(t, t, s01);
        t = a0.w - b1.w; s01 = fmaf(t, t, s01);
        t = a1.x - b0.x; s10 = fmaf(t, t, s10);
        t = a1.y - b0.y; s10 = fmaf(t, t, s10);
        t = a1.z - b0.z; s10 = fmaf(t, t, s10);
        t = a1.w - b0.w; s10 = fmaf(t, t, s10);
        t = a1.x - b1.x; s11 = fmaf(t, t, s11);
        t = a1.y - b1.y; s11 = fmaf(t, t, s11);
        t = a1.z - b1.z; s11 = fmaf(t, t, s11);
        t = a1.w - b1.w; s11 = fmaf(t, t, s11);
    }
    // safe_l2: identical rows give s == 0 exactly -> logit 0 (diagonal)
    float l00 = (s00 > 0.f) ? -0.5f * sqrtf(s00) : 0.f;
    float l01 = (s01 > 0.f) ? -0.5f * sqrtf(s01) : 0.f;
    float l10 = (s10 > 0.f) ? -0.5f * sqrtf(s10) : 0.f;
    float l11 = (s11 > 0.f) ? -0.5f * sqrtf(s11) : 0.f;

    *(float2*)(lg + (size_t)(row0 + r0) * N + col0 + c0) = make_float2(l00, l01);
    *(float2*)(lg + (size_t)(row0 + r1) * N + col0 + c0) = make_float2(l10, l11);
}

// ---------------- K2: per-row max, exp, class-combine (+ cnt reset) ----------------
__global__ __launch_bounds__(256) void k2_row(const float* __restrict__ lg,
                                              const float* __restrict__ labels,
                                              float* __restrict__ ld2,
                                              float* __restrict__ evs,
                                              float* __restrict__ rowsum,
                                              unsigned* __restrict__ cnt) {
    const int i = blockIdx.x;
    const int c = threadIdx.x;
    if (i == 0 && c == 0) *cnt = 0u;   // reset for K34's last-block pattern (graph-safe)

    const float la = lg[(size_t)i * N + c];
    const float lb = lg[(size_t)i * N + c + 256];

    // row max over j != i (lg[i][i] == 0 excluded)
    float m = -1e30f;
    if (c != i) m = la;
    if (c + 256 != i) m = fmaxf(m, lb);
    __shared__ float redm[4];
#pragma unroll
    for (int off = 32; off > 0; off >>= 1) m = fmaxf(m, __shfl_xor(m, off, 64));
    if ((c & 63) == 0) redm[c >> 6] = m;
    __syncthreads();
    m = fmaxf(fmaxf(redm[0], redm[1]), fmaxf(redm[2], redm[3]));

    // exp values; diagonal forced to 0 drops it from every denominator
    float ea = (c == i) ? 0.f : __expf(la - m);
    float eb = (c + 256 == i) ? 0.f : __expf(lb - m);
    evs[(size_t)i * C + c] = ea + eb;

    // label diff per class (bitwise identical to reference f32 math)
    const float2 lc2 = ((const float2*)labels)[c];
    const float2 li2 = ((const float2*)labels)[i & 255];
    ld2[(size_t)i * C + c] = fabsf(li2.x - lc2.x) + fabsf(li2.y - lc2.y);

    // rowsum = sum_{k != i}(lg_k - m) = (sum_k lg_k) - 511*m   (lg_i == 0)
    float s = la + lb;
    __shared__ float reds[4];
#pragma unroll
    for (int off = 32; off > 0; off >>= 1) s += __shfl_xor(s, off, 64);
    if ((c & 63) == 0) reds[c >> 6] = s;
    __syncthreads();
    if (c == 0) rowsum[i] = (reds[0] + reds[1] + reds[2] + reds[3]) - 511.f * m;
}

// ---------------- K34: class denominators + row loss + last-block final reduce ----------------
// Inner loop: wave-uniform scalar global reads of arrays written by a DIFFERENT
// kernel -> s_load path (proven in R4). Tail: int-counter last-block pattern,
// agent-scope release/acquire (cross-XCD safe), no contended FP atomics.
__global__ __launch_bounds__(256) void k34_den(const float* __restrict__ ld2,
                                               const float* __restrict__ evs,
                                               const float* __restrict__ rowsum,
                                               float* __restrict__ rowout,
                                               unsigned* __restrict__ cnt,
                                               float* __restrict__ out) {
    const int i = blockIdx.x;
    const int c = threadIdx.x;
    const float* __restrict__ rl = ld2 + (size_t)i * C;
    const float* __restrict__ re = evs + (size_t)i * C;
    const float ldk = rl[c];

    float d0 = 0.f, d1 = 0.f, d2 = 0.f, d3 = 0.f;
#pragma unroll 8
    for (int q = 0; q < C; q += 4) {
        float a0 = rl[q + 0], a1 = rl[q + 1], a2 = rl[q + 2], a3 = rl[q + 3];
        float b0 = re[q + 0], b1 = re[q + 1], b2 = re[q + 2], b3 = re[q + 3];
        d0 += (a0 >= ldk) ? b0 : 0.f;
        d1 += (a1 >= ldk) ? b1 : 0.f;
        d2 += (a2 >= ldk) ? b2 : 0.f;
        d3 += (a3 >= ldk) ? b3 : 0.f;
    }
    const float lden = __logf((d0 + d1) + (d2 + d3));

    __shared__ float red[4];
    __shared__ float lci;
    __shared__ int isLast;
    if (c == (i & 255)) lci = lden;   // class(i): ld == 0 -> den == total ev sum
    float s = lden;
#pragma unroll
    for (int off = 32; off > 0; off >>= 1) s += __shfl_xor(s, off, 64);
    if ((c & 63) == 0) red[c >> 6] = s;
    __syncthreads();
    if (c == 0) {
        const float tot = red[0] + red[1] + red[2] + red[3];
        const float part = rowsum[i] - (2.f * tot - lci);
        __hip_atomic_store(&rowout[i], part, __ATOMIC_RELEASE, __HIP_MEMORY_SCOPE_AGENT);
        const unsigned prev = __hip_atomic_fetch_add(cnt, 1u, __ATOMIC_ACQ_REL,
                                                     __HIP_MEMORY_SCOPE_AGENT);
        isLast = (prev == (unsigned)(N - 1));
    }
    __syncthreads();

    if (isLast) {   // block-uniform
        float v0 = __hip_atomic_load(&rowout[c], __ATOMIC_ACQUIRE, __HIP_MEMORY_SCOPE_AGENT);
        float v1 = __hip_atomic_load(&rowout[c + 256], __ATOMIC_ACQUIRE, __HIP_MEMORY_SCOPE_AGENT);
        double t = (double)v0 + (double)v1;
        __shared__ double sd[4];
#pragma unroll
        for (int off = 32; off > 0; off >>= 1) t += __shfl_down(t, off, 64);
        if ((c & 63) == 0) sd[c >> 6] = t;
        __syncthreads();
        if (c == 0) {
            double tot = sd[0] + sd[1] + sd[2] + sd[3];
            out[0] = (float)(-tot / ((double)N * (double)(N - 1)));
        }
    }
}

extern "C" void kernel_launch(void* const* d_in, const int* in_sizes, int n_in,
                              void* d_out, int out_size, void* d_ws, size_t ws_size,
                              hipStream_t stream) {
    const float* feat   = (const float*)d_in[0];   // [512,128] f32
    const float* labels = (const float*)d_in[1];   // [256,2]  f32
    float* out = (float*)d_out;

    float*    lg     = (float*)d_ws;               // N*N
    float*    ld2    = lg + (size_t)N * N;         // N*C
    float*    evs    = ld2 + (size_t)N * C;        // N*C
    float*    rowsum = evs + (size_t)N * C;        // N
    float*    rowout = rowsum + N;                 // N
    unsigned* cnt    = (unsigned*)(rowout + N);    // 1

    k1_logits<<<256, 256, 0, stream>>>(feat, lg);
    k2_row  <<<N,   256, 0, stream>>>(lg, labels, ld2, evs, rowsum, cnt);
    k34_den <<<N,   256, 0, stream>>>(ld2, evs, rowsum, rowout, cnt, out);
}

// Round 7
// 23.107 us; speedup vs baseline: 1.3252x; 1.3252x over previous
//
#include <hip/hip_runtime.h>
#include <math.h>

#define N 512
#define C 256          // distinct label-diff classes per row (labels repeat)
#define D 128

// ---------------- K1: all-pairs logits via LDS-staged 32x32 tiles ----------------
// (R4-proven body; block 0 additionally zeroes out[0] for K3's atomic tail)
__global__ __launch_bounds__(256) void k1_logits(const float* __restrict__ feat,
                                                 float* __restrict__ lg,
                                                 float* __restrict__ out) {
    const int tid = threadIdx.x;
    if (blockIdx.x == 0 && tid == 0) out[0] = 0.f;   // reset accumulator (graph-safe)

    const int row0 = (blockIdx.x >> 4) << 5;
    const int col0 = (blockIdx.x & 15) << 5;

    __shared__ float4 As[32][32];   // [row][swizzled q]
    __shared__ float4 Bs[32][32];

    const float4* f4 = (const float4*)feat;   // [512][32]
    {
        const int r = tid >> 5, c4 = tid & 31;
#pragma unroll
        for (int p = 0; p < 4; ++p) {
            const int rr = r + p * 8;
            const int sc = c4 ^ ((rr >> 1) & 7);
            As[rr][sc] = f4[(size_t)(row0 + rr) * 32 + c4];
            Bs[rr][sc] = f4[(size_t)(col0 + rr) * 32 + c4];
        }
    }
    __syncthreads();

    const int ty = tid >> 4, tx = tid & 15;
    const int r0 = 2 * ty, r1 = 2 * ty + 1;
    const int c0 = 2 * tx, c1 = 2 * tx + 1;
    const int sa = ty & 7, sb = tx & 7;

    float s00 = 0.f, s01 = 0.f, s10 = 0.f, s11 = 0.f;
#pragma unroll 8
    for (int q = 0; q < 32; ++q) {
        float4 a0 = As[r0][q ^ sa];
        float4 a1 = As[r1][q ^ sa];
        float4 b0 = Bs[c0][q ^ sb];
        float4 b1 = Bs[c1][q ^ sb];
        float t;
        t = a0.x - b0.x; s00 = fmaf(t, t, s00);
        t = a0.y - b0.y; s00 = fmaf(t, t, s00);
        t = a0.z - b0.z; s00 = fmaf(t, t, s00);
        t = a0.w - b0.w; s00 = fmaf(t, t, s00);
        t = a0.x - b1.x; s01 = fmaf(t, t, s01);
        t = a0.y - b1.y; s01 = fmaf(t, t, s01);
        t = a0.z - b1.z; s01 = fmaf(t, t, s01);
        t = a0.w - b1.w; s01 = fmaf(t, t, s01);
        t = a1.x - b0.x; s10 = fmaf(t, t, s10);
        t = a1.y - b0.y; s10 = fmaf(t, t, s10);
        t = a1.z - b0.z; s10 = fmaf(t, t, s10);
        t = a1.w - b0.w; s10 = fmaf(t, t, s10);
        t = a1.x - b1.x; s11 = fmaf(t, t, s11);
        t = a1.y - b1.y; s11 = fmaf(t, t, s11);
        t = a1.z - b1.z; s11 = fmaf(t, t, s11);
        t = a1.w - b1.w; s11 = fmaf(t, t, s11);
    }
    // safe_l2: identical rows give s == 0 exactly -> logit 0 (diagonal)
    float l00 = (s00 > 0.f) ? -0.5f * sqrtf(s00) : 0.f;
    float l01 = (s01 > 0.f) ? -0.5f * sqrtf(s01) : 0.f;
    float l10 = (s10 > 0.f) ? -0.5f * sqrtf(s10) : 0.f;
    float l11 = (s11 > 0.f) ? -0.5f * sqrtf(s11) : 0.f;

    *(float2*)(lg + (size_t)(row0 + r0) * N + col0 + c0) = make_float2(l00, l01);
    *(float2*)(lg + (size_t)(row0 + r1) * N + col0 + c0) = make_float2(l10, l11);
}

// ---------------- K2: per-row max, exp, class-combine ----------------
__global__ __launch_bounds__(256) void k2_row(const float* __restrict__ lg,
                                              const float* __restrict__ labels,
                                              float* __restrict__ ld2,
                                              float* __restrict__ evs,
                                              float* __restrict__ rowsum) {
    const int i = blockIdx.x;
    const int c = threadIdx.x;

    const float la = lg[(size_t)i * N + c];
    const float lb = lg[(size_t)i * N + c + 256];

    // row max over j != i (lg[i][i] == 0 excluded)
    float m = -1e30f;
    if (c != i) m = la;
    if (c + 256 != i) m = fmaxf(m, lb);
    __shared__ float redm[4];
#pragma unroll
    for (int off = 32; off > 0; off >>= 1) m = fmaxf(m, __shfl_xor(m, off, 64));
    if ((c & 63) == 0) redm[c >> 6] = m;
    __syncthreads();
    m = fmaxf(fmaxf(redm[0], redm[1]), fmaxf(redm[2], redm[3]));

    // exp values; diagonal forced to 0 drops it from every denominator
    float ea = (c == i) ? 0.f : __expf(la - m);
    float eb = (c + 256 == i) ? 0.f : __expf(lb - m);
    evs[(size_t)i * C + c] = ea + eb;

    // label diff per class (bitwise identical to reference f32 math)
    const float2 lc2 = ((const float2*)labels)[c];
    const float2 li2 = ((const float2*)labels)[i & 255];
    ld2[(size_t)i * C + c] = fabsf(li2.x - lc2.x) + fabsf(li2.y - lc2.y);

    // rowsum = sum_{k != i}(lg_k - m) = (sum_k lg_k) - 511*m   (lg_i == 0)
    float s = la + lb;
    __shared__ float reds[4];
#pragma unroll
    for (int off = 32; off > 0; off >>= 1) s += __shfl_xor(s, off, 64);
    if ((c & 63) == 0) reds[c >> 6] = s;
    __syncthreads();
    if (c == 0) rowsum[i] = (reds[0] + reds[1] + reds[2] + reds[3]) - 511.f * m;
}

// ---------------- K3: class denominators + row loss + plain atomic accumulate ----------------
// Inner loop: wave-uniform scalar global reads of arrays written by a DIFFERENT
// kernel -> s_load path (proven in R4). Tail: ONE plain device-scope float
// atomicAdd per block (no fences, no counter — R5/R6 showed ordered agent
// atomics cost more than a dispatch).
__global__ __launch_bounds__(256) void k3_den(const float* __restrict__ ld2,
                                              const float* __restrict__ evs,
                                              const float* __restrict__ rowsum,
                                              float* __restrict__ out) {
    const int i = blockIdx.x;
    const int c = threadIdx.x;
    const float* __restrict__ rl = ld2 + (size_t)i * C;
    const float* __restrict__ re = evs + (size_t)i * C;
    const float ldk = rl[c];

    float d0 = 0.f, d1 = 0.f, d2 = 0.f, d3 = 0.f;
#pragma unroll 8
    for (int q = 0; q < C; q += 4) {
        float a0 = rl[q + 0], a1 = rl[q + 1], a2 = rl[q + 2], a3 = rl[q + 3];
        float b0 = re[q + 0], b1 = re[q + 1], b2 = re[q + 2], b3 = re[q + 3];
        d0 += (a0 >= ldk) ? b0 : 0.f;
        d1 += (a1 >= ldk) ? b1 : 0.f;
        d2 += (a2 >= ldk) ? b2 : 0.f;
        d3 += (a3 >= ldk) ? b3 : 0.f;
    }
    const float lden = __logf((d0 + d1) + (d2 + d3));

    __shared__ float red[4];
    __shared__ float lci;
    if (c == (i & 255)) lci = lden;   // class(i): ld == 0 -> den == total ev sum
    float s = lden;
#pragma unroll
    for (int off = 32; off > 0; off >>= 1) s += __shfl_xor(s, off, 64);
    if ((c & 63) == 0) red[c >> 6] = s;
    __syncthreads();
    if (c == 0) {
        const float tot  = red[0] + red[1] + red[2] + red[3];
        const float part = rowsum[i] - (2.f * tot - lci);
        atomicAdd(out, part * (-1.0f / ((float)N * (float)(N - 1))));
    }
}

extern "C" void kernel_launch(void* const* d_in, const int* in_sizes, int n_in,
                              void* d_out, int out_size, void* d_ws, size_t ws_size,
                              hipStream_t stream) {
    const float* feat   = (const float*)d_in[0];   // [512,128] f32
    const float* labels = (const float*)d_in[1];   // [256,2]  f32
    float* out = (float*)d_out;

    float* lg     = (float*)d_ws;                  // N*N
    float* ld2    = lg + (size_t)N * N;            // N*C
    float* evs    = ld2 + (size_t)N * C;           // N*C
    float* rowsum = evs + (size_t)N * C;           // N

    k1_logits<<<256, 256, 0, stream>>>(feat, lg, out);
    k2_row  <<<N,   256, 0, stream>>>(lg, labels, ld2, evs, rowsum);
    k3_den  <<<N,   256, 0, stream>>>(ld2, evs, rowsum, out);
}